// Round 18
// baseline (128.744 us; speedup 1.0000x reference)
//
#include <hip/hip_runtime.h>
#include <hip/hip_bf16.h>

// Problem constants (B,S,D,H fixed by setup_inputs)
#define B_  8
#define S_  1024
#define D_  768
#define H_  12
#define DH_ 64

typedef __attribute__((ext_vector_type(8))) short bf16x8;
typedef __attribute__((ext_vector_type(4))) float f32x4;
typedef __attribute__((ext_vector_type(16))) float f32x16;

__device__ inline short f2bf(float f) {
    unsigned u = __builtin_bit_cast(unsigned, f);
    u = (u + 0x7fffu + ((u >> 16) & 1u)) >> 16;   // RNE
    return (short)u;
}
__device__ inline float exp2_fast(float x) {
    float r; asm("v_exp_f32 %0, %1" : "=v"(r) : "v"(x)); return r;
}
__device__ inline unsigned cvt_pk_bf16(float lo, float hi) {
    unsigned r; asm("v_cvt_pk_bf16_f32 %0, %1, %2" : "=v"(r) : "v"(lo), "v"(hi)); return r;
}
__device__ inline float rcp_fast(float x) {
    float r; asm("v_rcp_f32 %0, %1" : "=v"(r) : "v"(x)); return r;
}
__device__ inline void plswap(unsigned& a, unsigned& b) {
    auto r = __builtin_amdgcn_permlane32_swap(a, b, false, false);
    a = r[0]; b = r[1];
}
__device__ inline float2 xhalves(float x) {
    unsigned u = __builtin_bit_cast(unsigned, x);
    auto r = __builtin_amdgcn_permlane32_swap(u, u, false, false);
    return make_float2(__builtin_bit_cast(float, r[0]),
                       __builtin_bit_cast(float, r[1]));
}
// Async global->LDS, 16B/lane. LDS dest = wave-uniform base + lane*16;
// swizzle lives in the per-lane GLOBAL source address (rule 21).
__device__ inline void gl_lds16(const void* gsrc, char* ldst) {
    __builtin_amdgcn_global_load_lds(
        (const __attribute__((address_space(1))) unsigned int*)gsrc,
        (__attribute__((address_space(3))) unsigned int*)ldst,
        16, 0, 0);
}

// ---------------------------------------------------------------------------
// Kernel 0: W f32 -> bf16 (one-time). 589824 elems, 8 per thread.
// ---------------------------------------------------------------------------
__global__ __launch_bounds__(256) void convw_kernel(
    const float* __restrict__ W, short* __restrict__ Wb)
{
    int i = (blockIdx.x * 256 + threadIdx.x) * 8;
    f32x4 a = *(const f32x4*)(W + i);
    f32x4 b = *(const f32x4*)(W + i + 4);
    uint4 pk;
    pk.x = cvt_pk_bf16(a[0], a[1]); pk.y = cvt_pk_bf16(a[2], a[3]);
    pk.z = cvt_pk_bf16(b[0], b[1]); pk.w = cvt_pk_bf16(b[2], b[3]);
    *(uint4*)(Wb + i) = pk;
}

// ---------------------------------------------------------------------------
// Kernel 1 (v12): Y = relu(X @ W^T) — W-shared t-loop (v10) split into TWO
// independent barrier domains per CU. v10 (1 block/CU, 512 thr) achieved
// only 7.3 B/cyc/CU staging delivery because every vmcnt/barrier stall idles
// the whole CU; v6 (2 blocks/CU) demonstrated 11.2 B/cyc via cross-block
// overlap. v12: BM=64 x BN=192, 4 n-quarters x 128 m-pos = 512 blocks of
// 256 thr -> 2 blocks/CU. Staged traffic 264->377 MB but at >=11 B/cyc
// predicts ~55us (vs 66).
// - 4 waves; wave w owns cols [w*48,w*48+48); per-t acc[4][3]
// - per K-step: stage {X_q,X_k,X_v 8KB + W 12KB} = 36KB, dbuf 72KB LDS
// - per wave per step: 9 gl_lds (6 X + 3 W); counted vmcnt(9)
// ---------------------------------------------------------------------------
__global__ __launch_bounds__(256) void proj_kernel(
    const float* __restrict__ q, const float* __restrict__ k,
    const float* __restrict__ v, const short* __restrict__ Wb,
    short* __restrict__ q1, short* __restrict__ k1, short* __restrict__ v1t)
{
    __shared__ __align__(16) char lds[73728];
    // buf b at b*36864: X0@0 8K | X1@8192 | X2@16384 | W@24576 12K
    // epilogue overlay reuses [0,24K)

    int p  = blockIdx.x;
    int L  = (p & 7) * 64 + (p >> 3);        // 512 blocks = 8 XCD x 64
    int mt = L >> 2, nq = L & 3;             // 128 m-pos x 4 n-quarters
    int m0 = mt << 6;                        // row offset within EACH input
    int n0 = nq * 192;

    int tid = threadIdx.x, lane = tid & 63, w = tid >> 6;   // w 0..3
    int l15 = lane & 15, g = lane >> 4;

    // X staging: per wave 2 insts per input, rows [w*16, w*16+16)
    int xr0 = w * 16 + (lane >> 3), xr1 = xr0 + 8;
    int xc  = lane & 7;
    size_t xo0 = (size_t)(m0 + xr0) * D_ + ((xc ^ (xr0 & 7)) << 2);
    size_t xo1 = (size_t)(m0 + xr1) * D_ + ((xc ^ (xr1 & 7)) << 2);
    // W staging: per wave 3 insts, rows [w*48, w*48+48)
    int wr0 = w * 48 + (lane >> 2), wr1 = wr0 + 16, wr2 = wr0 + 32;
    int wc  = lane & 3;
    const short* ws0 = Wb + (size_t)(n0 + wr0) * D_ + ((wc ^ ((wr0 >> 1) & 3)) << 3);
    const short* ws1 = Wb + (size_t)(n0 + wr1) * D_ + ((wc ^ ((wr1 >> 1) & 3)) << 3);
    const short* ws2 = Wb + (size_t)(n0 + wr2) * D_ + ((wc ^ ((wr2 >> 1) & 3)) << 3);

#define ISSUE(s_, b_) do { int _ko = (s_) * 32; \
        char* _bb = lds + (b_) * 36864; \
        gl_lds16(q + xo0 + _ko, _bb + (w * 16) * 128); \
        gl_lds16(q + xo1 + _ko, _bb + (w * 16 + 8) * 128); \
        gl_lds16(k + xo0 + _ko, _bb + 8192 + (w * 16) * 128); \
        gl_lds16(k + xo1 + _ko, _bb + 8192 + (w * 16 + 8) * 128); \
        gl_lds16(v + xo0 + _ko, _bb + 16384 + (w * 16) * 128); \
        gl_lds16(v + xo1 + _ko, _bb + 16384 + (w * 16 + 8) * 128); \
        gl_lds16(ws0 + _ko, _bb + 24576 + (w * 48) * 64); \
        gl_lds16(ws1 + _ko, _bb + 24576 + (w * 48 + 16) * 64); \
        gl_lds16(ws2 + _ko, _bb + 24576 + (w * 48 + 32) * 64); \
    } while (0)

    f32x4 acc[3][4][3];
    #pragma unroll
    for (int t = 0; t < 3; t++)
        #pragma unroll
        for (int m = 0; m < 4; m++)
            #pragma unroll
            for (int n = 0; n < 3; n++) acc[t][m][n] = (f32x4){0.f, 0.f, 0.f, 0.f};

    ISSUE(0, 0);
    for (int s = 0; s < 24; ++s) {
        __builtin_amdgcn_s_barrier();            // reads of target buf done
        asm volatile("" ::: "memory");
        if (s + 1 < 24) {
            ISSUE(s + 1, (s + 1) & 1);
            asm volatile("s_waitcnt vmcnt(9)" ::: "memory");   // step-s landed
        } else {
            asm volatile("s_waitcnt vmcnt(0)" ::: "memory");
        }
        __builtin_amdgcn_s_barrier();            // all waves' loads landed
        asm volatile("" ::: "memory");

        const char* bb = lds + (s & 1) * 36864;
        const char* Wp = bb + 24576;
        bf16x8 bfv[3];
        #pragma unroll
        for (int n = 0; n < 3; n++) {
            int r = w * 48 + n * 16 + l15;
            bfv[n] = *(const bf16x8*)(Wp + r * 64 + ((g ^ ((r >> 1) & 3)) << 4));
        }
        #pragma unroll
        for (int t = 0; t < 3; t++) {
            const char* Xb = bb + t * 8192;
            bf16x8 af[4];
            #pragma unroll
            for (int m = 0; m < 4; m++) {
                int r = m * 16 + l15;
                const char* rp = Xb + r * 128;
                f32x4 lo = *(const f32x4*)(rp + (((2 * g)     ^ (r & 7)) << 4));
                f32x4 hi = *(const f32x4*)(rp + (((2 * g + 1) ^ (r & 7)) << 4));
                uint4 pk;
                pk.x = cvt_pk_bf16(lo[0], lo[1]); pk.y = cvt_pk_bf16(lo[2], lo[3]);
                pk.z = cvt_pk_bf16(hi[0], hi[1]); pk.w = cvt_pk_bf16(hi[2], hi[3]);
                af[m] = __builtin_bit_cast(bf16x8, pk);
            }
            __builtin_amdgcn_s_setprio(1);
            #pragma unroll
            for (int m = 0; m < 4; m++)
                #pragma unroll
                for (int n = 0; n < 3; n++)
                    acc[t][m][n] = __builtin_amdgcn_mfma_f32_16x16x32_bf16(
                        af[m], bfv[n], acc[t][m][n], 0, 0, 0);
            __builtin_amdgcn_s_setprio(0);
        }
    }
#undef ISSUE

    // Epilogue (per t): relu(+scale) -> bf16 -> swizzled overlay -> b128 stores.
    // q/k overlay: [64 rows][24 chunks16B] stride 384B, slot = ch ^ (row&7)
    // v overlay  : [192 cols][8 chunks16B]  stride 128B, slot = ch ^ (col&7)
    int bb2 = m0 >> 10;
    #pragma unroll
    for (int t = 0; t < 3; t++) {
        __syncthreads();
        const float sc1 = (t == 1) ? 0.18033688011112793f : 1.0f;  // 1/8*log2(e)
        #pragma unroll
        for (int m = 0; m < 4; m++)
            #pragma unroll
            for (int n = 0; n < 3; n++)
                #pragma unroll
                for (int r = 0; r < 4; r++) {
                    int row = m * 16 + g * 4 + r;
                    int col = w * 48 + n * 16 + l15;
                    short vv = f2bf(fmaxf(acc[t][m][n][r], 0.f) * sc1);
                    if (t == 2)   // v transposed: Tv[col 0..191][row 0..63]
                        *(short*)(lds + col * 128 + (((row >> 3) ^ (col & 7)) << 4)
                                  + ((row & 7) << 1)) = vv;
                    else          // Ts[row 0..63][col 0..191]
                        *(short*)(lds + row * 384 + (((col >> 3) ^ (row & 7)) << 4)
                                  + ((col & 7) << 1)) = vv;
                }
        __syncthreads();
        if (t == 2) {
            #pragma unroll
            for (int j = 0; j < 6; j++) {
                int c = tid * 6 + j;          // 1536 chunks: vr = c>>3, ch = c&7
                int vr = c >> 3, ch = c & 7;
                bf16x8 val = *(const bf16x8*)(lds + vr * 128 + ((ch ^ (vr & 7)) << 4));
                int gc = n0 + vr, h = gc >> 6, dh = gc & 63;
                *(bf16x8*)(v1t + (((size_t)bb2 * H_ + h) * DH_ + dh) * S_
                           + (m0 & 1023) + ch * 8) = val;
            }
        } else {
            short* dst0 = t ? k1 : q1;
            #pragma unroll
            for (int j = 0; j < 6; j++) {
                int c = tid * 6 + j;          // 1536 chunks: row = c/24, ch = c%24
                int row = c / 24, ch = c % 24;
                bf16x8 val = *(const bf16x8*)(lds + row * 384 + ((ch ^ (row & 7)) << 4));
                int m = m0 + row, ss = m & 1023;
                int gc = n0 + ch * 8, h = gc >> 6, dh = gc & 63;
                *(bf16x8*)(dst0 + (((size_t)bb2 * H_ + h) * S_ + ss) * DH_ + dh) = val;
            }
        }
    }
}

// ---------------------------------------------------------------------------
// Kernel 2 (v5): flash attention, swapped-QK^T 32x32x16, block-cooperative
// LDS-staged K/V (unchanged from round 6 -- passing, fast).
// ---------------------------------------------------------------------------
__global__ __launch_bounds__(256, 3) void attn_kernel(
    const short* __restrict__ q1, const short* __restrict__ k1,
    const short* __restrict__ v1t, float* __restrict__ out)
{
    __shared__ short Klds[2][4096];
    __shared__ short Vlds[2][4096];
    __shared__ float lsum_lds[4][32];

    int d    = blockIdx.x;
    int head = (d & 7) + ((d >> 6) << 3);
    int qi   = (d >> 3) & 7;
    int bb   = head / H_, hh = head % H_;

    int tid = threadIdx.x, lane = tid & 63, w = tid >> 6;
    int l31 = lane & 31, hi = lane >> 5;
    int qbase = (qi * 4 + w) * 32;

    const short* Qp = q1  + (size_t)head * S_ * DH_;
    const short* Kp = k1  + (size_t)head * S_ * DH_;
    const short* Vp = v1t + (size_t)head * DH_ * S_;

    int sr = tid >> 2, sc = tid & 3;
    int swz0 = sr * 128 + ((sc       ^ (sr & 7)) << 4);
    int swz1 = sr * 128 + (((sc + 4) ^ (sr & 7)) << 4);

    bf16x8 stK0, stK1, stV0, stV1;

#define LOADST(kvb) do { \
        const short* _kg = Kp + (size_t)((kvb) + sr) * DH_; \
        const short* _vg = Vp + (size_t)sr * S_ + (kvb); \
        stK0 = *(const bf16x8*)(_kg + sc * 8); \
        stK1 = *(const bf16x8*)(_kg + (sc + 4) * 8); \
        stV0 = *(const bf16x8*)(_vg + sc * 8); \
        stV1 = *(const bf16x8*)(_vg + (sc + 4) * 8); \
    } while (0)
#define WRITEST(buf) do { \
        char* _kb = (char*)&Klds[buf][0]; \
        char* _vb = (char*)&Vlds[buf][0]; \
        *(bf16x8*)(_kb + swz0) = stK0; \
        *(bf16x8*)(_kb + swz1) = stK1; \
        *(bf16x8*)(_vb + swz0) = stV0; \
        *(bf16x8*)(_vb + swz1) = stV1; \
    } while (0)

    bf16x8 qf[4];
    #pragma unroll
    for (int kb = 0; kb < 4; kb++)
        qf[kb] = *(const bf16x8*)(Qp + (size_t)(qbase + l31) * DH_ + kb * 16 + hi * 8);

    f32x16 o0, o1;
    #pragma unroll
    for (int r = 0; r < 16; r++) { o0[r] = 0.f; o1[r] = 0.f; }
    float mreg = -1e30f, lsum = 0.f;

    int xk = l31 & 7;

    auto subtile = [&](int cur, int j) {
        const char* Kt = (const char*)&Klds[cur][0];
        const char* Vt = (const char*)&Vlds[cur][0];
        int rK = (32 * j + l31) * 128;
        bf16x8 kf0 = *(const bf16x8*)(Kt + rK + (((0 + hi) ^ xk) << 4));
        bf16x8 kf1 = *(const bf16x8*)(Kt + rK + (((2 + hi) ^ xk) << 4));
        bf16x8 kf2 = *(const bf16x8*)(Kt + rK + (((4 + hi) ^ xk) << 4));
        bf16x8 kf3 = *(const bf16x8*)(Kt + rK + (((6 + hi) ^ xk) << 4));
        int rV0 = l31 * 128, rV1 = (32 + l31) * 128;
        int s0 = ((4 * j + hi) ^ xk) << 4, s1 = ((4 * j + 2 + hi) ^ xk) << 4;
        bf16x8 vf00 = *(const bf16x8*)(Vt + rV0 + s0);
        bf16x8 vf01 = *(const bf16x8*)(Vt + rV0 + s1);
        bf16x8 vf10 = *(const bf16x8*)(Vt + rV1 + s0);
        bf16x8 vf11 = *(const bf16x8*)(Vt + rV1 + s1);

        f32x16 s;
        #pragma unroll
        for (int r = 0; r < 16; r++) s[r] = 0.f;
        __builtin_amdgcn_s_setprio(1);
        s = __builtin_amdgcn_mfma_f32_32x32x16_bf16(kf0, qf[0], s, 0, 0, 0);
        s = __builtin_amdgcn_mfma_f32_32x32x16_bf16(kf1, qf[1], s, 0, 0, 0);
        s = __builtin_amdgcn_mfma_f32_32x32x16_bf16(kf2, qf[2], s, 0, 0, 0);
        s = __builtin_amdgcn_mfma_f32_32x32x16_bf16(kf3, qf[3], s, 0, 0, 0);
        __builtin_amdgcn_s_setprio(0);

        float t0 = fmaxf(s[0], s[1]),   t1 = fmaxf(s[2], s[3]);
        float t2 = fmaxf(s[4], s[5]),   t3 = fmaxf(s[6], s[7]);
        float t4 = fmaxf(s[8], s[9]),   t5 = fmaxf(s[10], s[11]);
        float t6 = fmaxf(s[12], s[13]), t7 = fmaxf(s[14], s[15]);
        float u0 = fmaxf(t0, t1), u1 = fmaxf(t2, t3);
        float u2 = fmaxf(t4, t5), u3 = fmaxf(t6, t7);
        float pmax = fmaxf(fmaxf(u0, u1), fmaxf(u2, u3));
        float2 ph = xhalves(pmax);
        pmax = fmaxf(ph.x, ph.y);

        if (!__all(pmax <= mreg + 8.f)) {
            float mn = fmaxf(mreg, pmax);
            float sc_ = exp2_fast(mreg - mn);
            mreg = mn; lsum *= sc_;
            if (hi == 0) lsum_lds[w][l31] = sc_;
            asm volatile("s_waitcnt lgkmcnt(0)" ::: "memory");
            #pragma unroll
            for (int r = 0; r < 16; r++) {
                int crow = (r & 3) + ((r >> 2) << 3) + (hi << 2);
                float srw = lsum_lds[w][crow];
                o0[r] *= srw; o1[r] *= srw;
            }
        }

        #pragma unroll
        for (int r = 0; r < 16; r++) s[r] = exp2_fast(s[r] - mreg);

        float a0 = s[0] + s[1],   a1 = s[2] + s[3];
        float a2 = s[4] + s[5],   a3 = s[6] + s[7];
        float a4 = s[8] + s[9],   a5 = s[10] + s[11];
        float a6 = s[12] + s[13], a7 = s[14] + s[15];
        float rsum = ((a0 + a1) + (a2 + a3)) + ((a4 + a5) + (a6 + a7));
        float2 rh = xhalves(rsum);
        lsum += rh.x + rh.y;

        unsigned c0 = cvt_pk_bf16(s[0], s[1]);
        unsigned c1 = cvt_pk_bf16(s[2], s[3]);
        unsigned c2 = cvt_pk_bf16(s[4], s[5]);
        unsigned c3 = cvt_pk_bf16(s[6], s[7]);
        unsigned c4 = cvt_pk_bf16(s[8], s[9]);
        unsigned c5 = cvt_pk_bf16(s[10], s[11]);
        unsigned c6 = cvt_pk_bf16(s[12], s[13]);
        unsigned c7 = cvt_pk_bf16(s[14], s[15]);
        plswap(c0, c2);
        plswap(c1, c3);
        plswap(c4, c6);
        plswap(c5, c7);

        union U { unsigned u[4]; bf16x8 v; };
        U f0, f1;
        f0.u[0] = c0; f0.u[1] = c1; f0.u[2] = c2; f0.u[3] = c3;
        f1.u[0] = c4; f1.u[1] = c5; f1.u[2] = c6; f1.u[3] = c7;

        __builtin_amdgcn_s_setprio(1);
        o0 = __builtin_amdgcn_mfma_f32_32x32x16_bf16(f0.v, vf00, o0, 0, 0, 0);
        o0 = __builtin_amdgcn_mfma_f32_32x32x16_bf16(f1.v, vf01, o0, 0, 0, 0);
        o1 = __builtin_amdgcn_mfma_f32_32x32x16_bf16(f0.v, vf10, o1, 0, 0, 0);
        o1 = __builtin_amdgcn_mfma_f32_32x32x16_bf16(f1.v, vf11, o1, 0, 0, 0);
        __builtin_amdgcn_s_setprio(0);
    };

    LOADST(0);
    WRITEST(0);
    LOADST(64);
    asm volatile("s_waitcnt lgkmcnt(0)" ::: "memory");
    __builtin_amdgcn_s_barrier();
    asm volatile("" ::: "memory");

    int cur = 0;
    for (int t = 0; t < 16; t++) {
        if (t < 15) {
            WRITEST(cur ^ 1);
            if (t < 14) LOADST((t + 2) * 64);
        }
        subtile(cur, 0);
        subtile(cur, 1);
        if (t < 15) {
            asm volatile("" ::: "memory");
            asm volatile("s_waitcnt lgkmcnt(0)" ::: "memory");
            __builtin_amdgcn_s_barrier();
            asm volatile("" ::: "memory");
        }
        cur ^= 1;
    }
#undef LOADST
#undef WRITEST

    if (hi == 0) lsum_lds[w][l31] = lsum;
    asm volatile("s_waitcnt lgkmcnt(0)" ::: "memory");
    #pragma unroll
    for (int r = 0; r < 16; r++) {
        int crow = (r & 3) + ((r >> 2) << 3) + (hi << 2);
        float inv = rcp_fast(lsum_lds[w][crow]);
        float* op = out + ((size_t)(bb * S_ + qbase + crow)) * D_ + hh * DH_ + l31;
        op[0]  = o0[r] * inv;
        op[32] = o1[r] * inv;
    }
}

// ---------------------------------------------------------------------------
// Kernel 3 (v2): y = LN(2*out + q) * gamma + beta; 192 thr/row, f32x4 loads.
// ---------------------------------------------------------------------------
__global__ __launch_bounds__(192) void ln_kernel(
    const float* __restrict__ qin, const float* __restrict__ gamma,
    const float* __restrict__ beta, float* __restrict__ out)
{
    int row = blockIdx.x;
    int tid = threadIdx.x;
    size_t base = (size_t)row * D_ + tid * 4;

    f32x4 o  = *(const f32x4*)(out + base);
    f32x4 qv = *(const f32x4*)(qin + base);
    f32x4 x;
    float sum = 0.f, sq = 0.f;
    #pragma unroll
    for (int i = 0; i < 4; i++) {
        x[i] = 2.f * o[i] + qv[i];
        sum += x[i];
        sq  += x[i] * x[i];
    }
    #pragma unroll
    for (int msk = 1; msk < 64; msk <<= 1) {
        sum += __shfl_xor(sum, msk);
        sq  += __shfl_xor(sq, msk);
    }
    __shared__ float s1[3], s2[3];
    if ((tid & 63) == 0) { s1[tid >> 6] = sum; s2[tid >> 6] = sq; }
    __syncthreads();
    sum = s1[0] + s1[1] + s1[2];
    sq  = s2[0] + s2[1] + s2[2];
    float mu   = sum * (1.f / D_);
    float var  = sq * (1.f / D_) - mu * mu;
    float rstd = rsqrtf(var + 1e-5f);
    f32x4 g = *(const f32x4*)(gamma + tid * 4);
    f32x4 b = *(const f32x4*)(beta + tid * 4);
    f32x4 y;
    #pragma unroll
    for (int i = 0; i < 4; i++)
        y[i] = (x[i] - mu) * rstd * g[i] + b[i];
    *(f32x4*)(out + base) = y;
}

// ---------------------------------------------------------------------------
extern "C" void kernel_launch(void* const* d_in, const int* in_sizes, int n_in,
                              void* d_out, int out_size, void* d_ws, size_t ws_size,
                              hipStream_t stream)
{
    const float* q     = (const float*)d_in[0];
    const float* k     = (const float*)d_in[1];
    const float* v     = (const float*)d_in[2];
    const float* W     = (const float*)d_in[3];
    const float* gamma = (const float*)d_in[4];
    const float* beta  = (const float*)d_in[5];

    size_t per = (size_t)B_ * H_ * S_ * DH_;   // 6291456
    short* q1  = (short*)d_ws;
    short* k1  = q1 + per;
    short* v1t = k1 + per;
    short* Wb  = v1t + per;                    // +1.18 MB (total ~38.9 MB)
    float* out = (float*)d_out;

    convw_kernel<<<dim3(288), dim3(256), 0, stream>>>(W, Wb);
    // 128 m-positions x 4 n-quarters = 512 blocks, 256 threads, all 3 inputs
    proj_kernel<<<dim3(512), dim3(256), 0, stream>>>(q, k, v, Wb, q1, k1, v1t);
    attn_kernel<<<dim3(768), dim3(256), 0, stream>>>(q1, k1, v1t, out);
    ln_kernel<<<dim3(B_ * S_), dim3(192), 0, stream>>>(q, gamma, beta, out);
}

// Round 19
// 109.947 us; speedup vs baseline: 1.1710x; 1.1710x over previous
//
#include <hip/hip_runtime.h>
#include <hip/hip_bf16.h>

// Problem constants (B,S,D,H fixed by setup_inputs)
#define B_  8
#define S_  1024
#define D_  768
#define H_  12
#define DH_ 64

typedef __attribute__((ext_vector_type(8))) short bf16x8;
typedef __attribute__((ext_vector_type(4))) float f32x4;
typedef __attribute__((ext_vector_type(16))) float f32x16;

__device__ inline short f2bf(float f) {
    unsigned u = __builtin_bit_cast(unsigned, f);
    u = (u + 0x7fffu + ((u >> 16) & 1u)) >> 16;   // RNE
    return (short)u;
}
__device__ inline float exp2_fast(float x) {
    float r; asm("v_exp_f32 %0, %1" : "=v"(r) : "v"(x)); return r;
}
__device__ inline unsigned cvt_pk_bf16(float lo, float hi) {
    unsigned r; asm("v_cvt_pk_bf16_f32 %0, %1, %2" : "=v"(r) : "v"(lo), "v"(hi)); return r;
}
__device__ inline float rcp_fast(float x) {
    float r; asm("v_rcp_f32 %0, %1" : "=v"(r) : "v"(x)); return r;
}
__device__ inline void plswap(unsigned& a, unsigned& b) {
    auto r = __builtin_amdgcn_permlane32_swap(a, b, false, false);
    a = r[0]; b = r[1];
}
__device__ inline float2 xhalves(float x) {
    unsigned u = __builtin_bit_cast(unsigned, x);
    auto r = __builtin_amdgcn_permlane32_swap(u, u, false, false);
    return make_float2(__builtin_bit_cast(float, r[0]),
                       __builtin_bit_cast(float, r[1]));
}
// Async global->LDS, 16B/lane. LDS dest = wave-uniform base + lane*16;
// swizzle lives in the per-lane GLOBAL source address (rule 21).
__device__ inline void gl_lds16(const void* gsrc, char* ldst) {
    __builtin_amdgcn_global_load_lds(
        (const __attribute__((address_space(1))) unsigned int*)gsrc,
        (__attribute__((address_space(3))) unsigned int*)ldst,
        16, 0, 0);
}

// ---------------------------------------------------------------------------
// Kernel 0: W f32 -> bf16 (one-time). 589824 elems, 8 per thread.
// ---------------------------------------------------------------------------
__global__ __launch_bounds__(256) void convw_kernel(
    const float* __restrict__ W, short* __restrict__ Wb)
{
    int i = (blockIdx.x * 256 + threadIdx.x) * 8;
    f32x4 a = *(const f32x4*)(W + i);
    f32x4 b = *(const f32x4*)(W + i + 4);
    uint4 pk;
    pk.x = cvt_pk_bf16(a[0], a[1]); pk.y = cvt_pk_bf16(a[2], a[3]);
    pk.z = cvt_pk_bf16(b[0], b[1]); pk.w = cvt_pk_bf16(b[2], b[3]);
    *(uint4*)(Wb + i) = pk;
}

// ---------------------------------------------------------------------------
// Kernel 1 (v10, FINAL — best measured 66-67us): Y = relu(X @ W^T).
// W SHARED across q,k,v (t-loop inside K-step): W staged once per K-step,
// consumed 3x. Staged traffic 295 MB (constrained optimum). Grid 256 =
// 1 block/CU, single residency round. Bracketing experiments: deeper
// prefetch (R16) null; 2-barrier-domain split (R18) regressed; byte-traffic
// alternatives (R9-R13) all slower. This is the structure-family optimum.
// ---------------------------------------------------------------------------
__global__ __launch_bounds__(512) void proj_kernel(
    const float* __restrict__ q, const float* __restrict__ k,
    const float* __restrict__ v, const short* __restrict__ Wb,
    short* __restrict__ q1, short* __restrict__ k1, short* __restrict__ v1t)
{
    __shared__ __align__(16) char lds[98304];
    // buf b at b*49152: X0@0 8K | X1@8192 | X2@16384 | W@24576 24K
    // epilogue overlay reuses [0,48K)

    int p  = blockIdx.x;
    int L  = (p & 7) * 32 + (p >> 3);        // 256 blocks = 8 XCD x 32
    int mt = L >> 1, nb = L & 1;             // 128 m-pos x 2 n-halves
    int m0 = mt << 6;                        // row offset within EACH input
    int n0 = nb * 384;

    int tid = threadIdx.x, lane = tid & 63, w = tid >> 6;   // w 0..7
    int l15 = lane & 15, g = lane >> 4;

    // X staging source (per-lane, pre-swizzled; same pattern all t)
    int xrow = w * 8 + (lane >> 3), xc = lane & 7;
    size_t xoff = (size_t)(m0 + xrow) * D_ + ((xc ^ (xrow & 7)) << 2);
    const float* xs0 = q + xoff;
    const float* xs1 = k + xoff;
    const float* xs2 = v + xoff;
    // W staging
    int wrow0 = w * 48 + (lane >> 2), wc = lane & 3;
    int wrow1 = wrow0 + 16, wrow2 = wrow0 + 32;
    const short* wsrc0 = Wb + (size_t)(n0 + wrow0) * D_ + ((wc ^ ((wrow0 >> 1) & 3)) << 3);
    const short* wsrc1 = Wb + (size_t)(n0 + wrow1) * D_ + ((wc ^ ((wrow1 >> 1) & 3)) << 3);
    const short* wsrc2 = Wb + (size_t)(n0 + wrow2) * D_ + ((wc ^ ((wrow2 >> 1) & 3)) << 3);

#define ISSUE(s_, b_) do { int _ko = (s_) * 32; \
        char* _bb = lds + (b_) * 49152; \
        gl_lds16(xs0 + _ko, _bb + w * 1024); \
        gl_lds16(xs1 + _ko, _bb + 8192 + w * 1024); \
        gl_lds16(xs2 + _ko, _bb + 16384 + w * 1024); \
        gl_lds16(wsrc0 + _ko, _bb + 24576 + w * 3072); \
        gl_lds16(wsrc1 + _ko, _bb + 24576 + w * 3072 + 1024); \
        gl_lds16(wsrc2 + _ko, _bb + 24576 + w * 3072 + 2048); \
    } while (0)

    f32x4 acc[3][4][3];
    #pragma unroll
    for (int t = 0; t < 3; t++)
        #pragma unroll
        for (int m = 0; m < 4; m++)
            #pragma unroll
            for (int n = 0; n < 3; n++) acc[t][m][n] = (f32x4){0.f, 0.f, 0.f, 0.f};

    ISSUE(0, 0);
    for (int s = 0; s < 24; ++s) {
        __builtin_amdgcn_s_barrier();            // reads of target buf done
        asm volatile("" ::: "memory");
        if (s + 1 < 24) {
            ISSUE(s + 1, (s + 1) & 1);
            asm volatile("s_waitcnt vmcnt(6)" ::: "memory");   // step-s landed
        } else {
            asm volatile("s_waitcnt vmcnt(0)" ::: "memory");
        }
        __builtin_amdgcn_s_barrier();            // all waves' loads landed
        asm volatile("" ::: "memory");

        const char* bb = lds + (s & 1) * 49152;
        const char* Wp = bb + 24576;
        bf16x8 bfv[3];
        #pragma unroll
        for (int n = 0; n < 3; n++) {
            int r = w * 48 + n * 16 + l15;
            bfv[n] = *(const bf16x8*)(Wp + r * 64 + ((g ^ ((r >> 1) & 3)) << 4));
        }
        #pragma unroll
        for (int t = 0; t < 3; t++) {
            const char* Xb = bb + t * 8192;
            bf16x8 af[4];
            #pragma unroll
            for (int m = 0; m < 4; m++) {
                int r = m * 16 + l15;
                const char* rp = Xb + r * 128;
                f32x4 lo = *(const f32x4*)(rp + (((2 * g)     ^ (r & 7)) << 4));
                f32x4 hi = *(const f32x4*)(rp + (((2 * g + 1) ^ (r & 7)) << 4));
                uint4 pk;
                pk.x = cvt_pk_bf16(lo[0], lo[1]); pk.y = cvt_pk_bf16(lo[2], lo[3]);
                pk.z = cvt_pk_bf16(hi[0], hi[1]); pk.w = cvt_pk_bf16(hi[2], hi[3]);
                af[m] = __builtin_bit_cast(bf16x8, pk);
            }
            __builtin_amdgcn_s_setprio(1);
            #pragma unroll
            for (int m = 0; m < 4; m++)
                #pragma unroll
                for (int n = 0; n < 3; n++)
                    acc[t][m][n] = __builtin_amdgcn_mfma_f32_16x16x32_bf16(
                        af[m], bfv[n], acc[t][m][n], 0, 0, 0);
            __builtin_amdgcn_s_setprio(0);
        }
    }
#undef ISSUE

    // Epilogue (per t): relu(+scale) -> bf16 -> swizzled overlay -> b128 stores.
    // q/k overlay: [64 rows][48 chunks16B], slot = ch ^ (row&7)  (48KB)
    // v overlay  : [384 rows][8 chunks16B], slot = ch ^ (row&7)  (48KB)
    int bb2 = m0 >> 10;
    #pragma unroll
    for (int t = 0; t < 3; t++) {
        __syncthreads();
        const float sc1 = (t == 1) ? 0.18033688011112793f : 1.0f;  // 1/8*log2(e)
        #pragma unroll
        for (int m = 0; m < 4; m++)
            #pragma unroll
            for (int n = 0; n < 3; n++)
                #pragma unroll
                for (int r = 0; r < 4; r++) {
                    int row = m * 16 + g * 4 + r;
                    int col = w * 48 + n * 16 + l15;
                    short vv = f2bf(fmaxf(acc[t][m][n][r], 0.f) * sc1);
                    if (t == 2)   // v transposed: Ts[col 0..383][row 0..63]
                        *(short*)(lds + col * 128 + (((row >> 3) ^ (col & 7)) << 4)
                                  + ((row & 7) << 1)) = vv;
                    else          // Ts[row 0..63][col 0..383]
                        *(short*)(lds + row * 768 + (((col >> 3) ^ (row & 7)) << 4)
                                  + ((col & 7) << 1)) = vv;
                }
        __syncthreads();
        if (t == 2) {
            #pragma unroll
            for (int j = 0; j < 6; j++) {
                int c = tid * 6 + j;          // 3072 chunks: vr = c>>3, ch = c&7
                int vr = c >> 3, ch = c & 7;
                bf16x8 val = *(const bf16x8*)(lds + vr * 128 + ((ch ^ (vr & 7)) << 4));
                int gc = n0 + vr, h = gc >> 6, dh = gc & 63;
                *(bf16x8*)(v1t + (((size_t)bb2 * H_ + h) * DH_ + dh) * S_
                           + (m0 & 1023) + ch * 8) = val;
            }
        } else {
            short* dst0 = t ? k1 : q1;
            #pragma unroll
            for (int j = 0; j < 6; j++) {
                int c = tid * 6 + j;          // 3072 chunks: row = c/48, ch = c%48
                int row = c / 48, ch = c % 48;
                bf16x8 val = *(const bf16x8*)(lds + row * 768 + ((ch ^ (row & 7)) << 4));
                int m = m0 + row, ss = m & 1023;
                int gc = n0 + ch * 8, h = gc >> 6, dh = gc & 63;
                *(bf16x8*)(dst0 + (((size_t)bb2 * H_ + h) * S_ + ss) * DH_ + dh) = val;
            }
        }
    }
}

// ---------------------------------------------------------------------------
// Kernel 2 (v5): flash attention, swapped-QK^T 32x32x16, block-cooperative
// LDS-staged K/V (unchanged from round 6 -- passing, fast).
// ---------------------------------------------------------------------------
__global__ __launch_bounds__(256, 3) void attn_kernel(
    const short* __restrict__ q1, const short* __restrict__ k1,
    const short* __restrict__ v1t, float* __restrict__ out)
{
    __shared__ short Klds[2][4096];
    __shared__ short Vlds[2][4096];
    __shared__ float lsum_lds[4][32];

    int d    = blockIdx.x;
    int head = (d & 7) + ((d >> 6) << 3);
    int qi   = (d >> 3) & 7;
    int bb   = head / H_, hh = head % H_;

    int tid = threadIdx.x, lane = tid & 63, w = tid >> 6;
    int l31 = lane & 31, hi = lane >> 5;
    int qbase = (qi * 4 + w) * 32;

    const short* Qp = q1  + (size_t)head * S_ * DH_;
    const short* Kp = k1  + (size_t)head * S_ * DH_;
    const short* Vp = v1t + (size_t)head * DH_ * S_;

    int sr = tid >> 2, sc = tid & 3;
    int swz0 = sr * 128 + ((sc       ^ (sr & 7)) << 4);
    int swz1 = sr * 128 + (((sc + 4) ^ (sr & 7)) << 4);

    bf16x8 stK0, stK1, stV0, stV1;

#define LOADST(kvb) do { \
        const short* _kg = Kp + (size_t)((kvb) + sr) * DH_; \
        const short* _vg = Vp + (size_t)sr * S_ + (kvb); \
        stK0 = *(const bf16x8*)(_kg + sc * 8); \
        stK1 = *(const bf16x8*)(_kg + (sc + 4) * 8); \
        stV0 = *(const bf16x8*)(_vg + sc * 8); \
        stV1 = *(const bf16x8*)(_vg + (sc + 4) * 8); \
    } while (0)
#define WRITEST(buf) do { \
        char* _kb = (char*)&Klds[buf][0]; \
        char* _vb = (char*)&Vlds[buf][0]; \
        *(bf16x8*)(_kb + swz0) = stK0; \
        *(bf16x8*)(_kb + swz1) = stK1; \
        *(bf16x8*)(_vb + swz0) = stV0; \
        *(bf16x8*)(_vb + swz1) = stV1; \
    } while (0)

    bf16x8 qf[4];
    #pragma unroll
    for (int kb = 0; kb < 4; kb++)
        qf[kb] = *(const bf16x8*)(Qp + (size_t)(qbase + l31) * DH_ + kb * 16 + hi * 8);

    f32x16 o0, o1;
    #pragma unroll
    for (int r = 0; r < 16; r++) { o0[r] = 0.f; o1[r] = 0.f; }
    float mreg = -1e30f, lsum = 0.f;

    int xk = l31 & 7;

    auto subtile = [&](int cur, int j) {
        const char* Kt = (const char*)&Klds[cur][0];
        const char* Vt = (const char*)&Vlds[cur][0];
        int rK = (32 * j + l31) * 128;
        bf16x8 kf0 = *(const bf16x8*)(Kt + rK + (((0 + hi) ^ xk) << 4));
        bf16x8 kf1 = *(const bf16x8*)(Kt + rK + (((2 + hi) ^ xk) << 4));
        bf16x8 kf2 = *(const bf16x8*)(Kt + rK + (((4 + hi) ^ xk) << 4));
        bf16x8 kf3 = *(const bf16x8*)(Kt + rK + (((6 + hi) ^ xk) << 4));
        int rV0 = l31 * 128, rV1 = (32 + l31) * 128;
        int s0 = ((4 * j + hi) ^ xk) << 4, s1 = ((4 * j + 2 + hi) ^ xk) << 4;
        bf16x8 vf00 = *(const bf16x8*)(Vt + rV0 + s0);
        bf16x8 vf01 = *(const bf16x8*)(Vt + rV0 + s1);
        bf16x8 vf10 = *(const bf16x8*)(Vt + rV1 + s0);
        bf16x8 vf11 = *(const bf16x8*)(Vt + rV1 + s1);

        f32x16 s;
        #pragma unroll
        for (int r = 0; r < 16; r++) s[r] = 0.f;
        __builtin_amdgcn_s_setprio(1);
        s = __builtin_amdgcn_mfma_f32_32x32x16_bf16(kf0, qf[0], s, 0, 0, 0);
        s = __builtin_amdgcn_mfma_f32_32x32x16_bf16(kf1, qf[1], s, 0, 0, 0);
        s = __builtin_amdgcn_mfma_f32_32x32x16_bf16(kf2, qf[2], s, 0, 0, 0);
        s = __builtin_amdgcn_mfma_f32_32x32x16_bf16(kf3, qf[3], s, 0, 0, 0);
        __builtin_amdgcn_s_setprio(0);

        float t0 = fmaxf(s[0], s[1]),   t1 = fmaxf(s[2], s[3]);
        float t2 = fmaxf(s[4], s[5]),   t3 = fmaxf(s[6], s[7]);
        float t4 = fmaxf(s[8], s[9]),   t5 = fmaxf(s[10], s[11]);
        float t6 = fmaxf(s[12], s[13]), t7 = fmaxf(s[14], s[15]);
        float u0 = fmaxf(t0, t1), u1 = fmaxf(t2, t3);
        float u2 = fmaxf(t4, t5), u3 = fmaxf(t6, t7);
        float pmax = fmaxf(fmaxf(u0, u1), fmaxf(u2, u3));
        float2 ph = xhalves(pmax);
        pmax = fmaxf(ph.x, ph.y);

        if (!__all(pmax <= mreg + 8.f)) {
            float mn = fmaxf(mreg, pmax);
            float sc_ = exp2_fast(mreg - mn);
            mreg = mn; lsum *= sc_;
            if (hi == 0) lsum_lds[w][l31] = sc_;
            asm volatile("s_waitcnt lgkmcnt(0)" ::: "memory");
            #pragma unroll
            for (int r = 0; r < 16; r++) {
                int crow = (r & 3) + ((r >> 2) << 3) + (hi << 2);
                float srw = lsum_lds[w][crow];
                o0[r] *= srw; o1[r] *= srw;
            }
        }

        #pragma unroll
        for (int r = 0; r < 16; r++) s[r] = exp2_fast(s[r] - mreg);

        float a0 = s[0] + s[1],   a1 = s[2] + s[3];
        float a2 = s[4] + s[5],   a3 = s[6] + s[7];
        float a4 = s[8] + s[9],   a5 = s[10] + s[11];
        float a6 = s[12] + s[13], a7 = s[14] + s[15];
        float rsum = ((a0 + a1) + (a2 + a3)) + ((a4 + a5) + (a6 + a7));
        float2 rh = xhalves(rsum);
        lsum += rh.x + rh.y;

        unsigned c0 = cvt_pk_bf16(s[0], s[1]);
        unsigned c1 = cvt_pk_bf16(s[2], s[3]);
        unsigned c2 = cvt_pk_bf16(s[4], s[5]);
        unsigned c3 = cvt_pk_bf16(s[6], s[7]);
        unsigned c4 = cvt_pk_bf16(s[8], s[9]);
        unsigned c5 = cvt_pk_bf16(s[10], s[11]);
        unsigned c6 = cvt_pk_bf16(s[12], s[13]);
        unsigned c7 = cvt_pk_bf16(s[14], s[15]);
        plswap(c0, c2);
        plswap(c1, c3);
        plswap(c4, c6);
        plswap(c5, c7);

        union U { unsigned u[4]; bf16x8 v; };
        U f0, f1;
        f0.u[0] = c0; f0.u[1] = c1; f0.u[2] = c2; f0.u[3] = c3;
        f1.u[0] = c4; f1.u[1] = c5; f1.u[2] = c6; f1.u[3] = c7;

        __builtin_amdgcn_s_setprio(1);
        o0 = __builtin_amdgcn_mfma_f32_32x32x16_bf16(f0.v, vf00, o0, 0, 0, 0);
        o0 = __builtin_amdgcn_mfma_f32_32x32x16_bf16(f1.v, vf01, o0, 0, 0, 0);
        o1 = __builtin_amdgcn_mfma_f32_32x32x16_bf16(f0.v, vf10, o1, 0, 0, 0);
        o1 = __builtin_amdgcn_mfma_f32_32x32x16_bf16(f1.v, vf11, o1, 0, 0, 0);
        __builtin_amdgcn_s_setprio(0);
    };

    LOADST(0);
    WRITEST(0);
    LOADST(64);
    asm volatile("s_waitcnt lgkmcnt(0)" ::: "memory");
    __builtin_amdgcn_s_barrier();
    asm volatile("" ::: "memory");

    int cur = 0;
    for (int t = 0; t < 16; t++) {
        if (t < 15) {
            WRITEST(cur ^ 1);
            if (t < 14) LOADST((t + 2) * 64);
        }
        subtile(cur, 0);
        subtile(cur, 1);
        if (t < 15) {
            asm volatile("" ::: "memory");
            asm volatile("s_waitcnt lgkmcnt(0)" ::: "memory");
            __builtin_amdgcn_s_barrier();
            asm volatile("" ::: "memory");
        }
        cur ^= 1;
    }
#undef LOADST
#undef WRITEST

    if (hi == 0) lsum_lds[w][l31] = lsum;
    asm volatile("s_waitcnt lgkmcnt(0)" ::: "memory");
    #pragma unroll
    for (int r = 0; r < 16; r++) {
        int crow = (r & 3) + ((r >> 2) << 3) + (hi << 2);
        float inv = rcp_fast(lsum_lds[w][crow]);
        float* op = out + ((size_t)(bb * S_ + qbase + crow)) * D_ + hh * DH_ + l31;
        op[0]  = o0[r] * inv;
        op[32] = o1[r] * inv;
    }
}

// ---------------------------------------------------------------------------
// Kernel 3 (v2): y = LN(2*out + q) * gamma + beta; 192 thr/row, f32x4 loads.
// ---------------------------------------------------------------------------
__global__ __launch_bounds__(192) void ln_kernel(
    const float* __restrict__ qin, const float* __restrict__ gamma,
    const float* __restrict__ beta, float* __restrict__ out)
{
    int row = blockIdx.x;
    int tid = threadIdx.x;
    size_t base = (size_t)row * D_ + tid * 4;

    f32x4 o  = *(const f32x4*)(out + base);
    f32x4 qv = *(const f32x4*)(qin + base);
    f32x4 x;
    float sum = 0.f, sq = 0.f;
    #pragma unroll
    for (int i = 0; i < 4; i++) {
        x[i] = 2.f * o[i] + qv[i];
        sum += x[i];
        sq  += x[i] * x[i];
    }
    #pragma unroll
    for (int msk = 1; msk < 64; msk <<= 1) {
        sum += __shfl_xor(sum, msk);
        sq  += __shfl_xor(sq, msk);
    }
    __shared__ float s1[3], s2[3];
    if ((tid & 63) == 0) { s1[tid >> 6] = sum; s2[tid >> 6] = sq; }
    __syncthreads();
    sum = s1[0] + s1[1] + s1[2];
    sq  = s2[0] + s2[1] + s2[2];
    float mu   = sum * (1.f / D_);
    float var  = sq * (1.f / D_) - mu * mu;
    float rstd = rsqrtf(var + 1e-5f);
    f32x4 g = *(const f32x4*)(gamma + tid * 4);
    f32x4 b = *(const f32x4*)(beta + tid * 4);
    f32x4 y;
    #pragma unroll
    for (int i = 0; i < 4; i++)
        y[i] = (x[i] - mu) * rstd * g[i] + b[i];
    *(f32x4*)(out + base) = y;
}

// ---------------------------------------------------------------------------
extern "C" void kernel_launch(void* const* d_in, const int* in_sizes, int n_in,
                              void* d_out, int out_size, void* d_ws, size_t ws_size,
                              hipStream_t stream)
{
    const float* q     = (const float*)d_in[0];
    const float* k     = (const float*)d_in[1];
    const float* v     = (const float*)d_in[2];
    const float* W     = (const float*)d_in[3];
    const float* gamma = (const float*)d_in[4];
    const float* beta  = (const float*)d_in[5];

    size_t per = (size_t)B_ * H_ * S_ * DH_;   // 6291456
    short* q1  = (short*)d_ws;
    short* k1  = q1 + per;
    short* v1t = k1 + per;
    short* Wb  = v1t + per;                    // +1.18 MB (total ~38.9 MB)
    float* out = (float*)d_out;

    convw_kernel<<<dim3(288), dim3(256), 0, stream>>>(W, Wb);
    // 128 m-positions x 2 n-halves = 256 blocks, 512 threads, all 3 inputs each
    proj_kernel<<<dim3(256), dim3(512), 0, stream>>>(q, k, v, Wb, q1, k1, v1t);
    attn_kernel<<<dim3(768), dim3(256), 0, stream>>>(q1, k1, v1t, out);
    ln_kernel<<<dim3(B_ * S_), dim3(192), 0, stream>>>(q, gamma, beta, out);
}